// Round 8
// baseline (4463.955 us; speedup 1.0000x reference)
//
#include <hip/hip_runtime.h>

// ---------------------------------------------------------------------------
// Sizes
// ---------------------------------------------------------------------------
#define BB 32
#define TT 1024
#define II 64
#define HH 512
#define FF 63
#define G4H 2048         // 4*H
#define KK 576           // H + I (concat [h | x])
#define MM 32768         // B*T
#define NW 32            // worker blocks (each owns 16 cells)

// out layout (elements): state[B,T,63] | reward[B,T] | hT[B,H] | cT[B,H]
#define RW_OFF 2064384
#define HT_OFF 2097152
#define CT_OFF 2113536

// ws layout (bytes)
#define WS_FLAGS   0            // u32[NW][4] @128-B stride: per-WAVE step posts
#define WS_FLAG    4096         // u32 (1 = inputs are fp32)
#define WS_TICK    4224         // u32[8] per-XCD ticket counters
#define WS_CHOSEN  4288         // u32: 0 = undecided, else winning xcc+1
#define WS_TICK2   4352         // u32: loser-block job ticket (combine work)
#define WS_BIASC   8448         // f32[2048]
#define WS_BSH     16640        // f32[512]
#define WS_BCSA    18688        // f32[512]   (bcsa|bcra contiguous)
#define WS_BCRA    20736        // f32[512]
#define WS_BCH     22784        // f32[64]
#define WS_SCAL    23040        // f32[2]: bv_sa, bv_ra
#define WS_VS      23168        // bf16[512]  (vs|vr contiguous)
#define WS_VR      24192        // bf16[512]
#define WS_ZB      25216        // f32[512] zeros
#define WS_H0      27264        // bf16[32][512]  (h0 slab)
#define WS_CP      60032        // bf16[32][512] (c0 converted)
#define WS_WHPAD   92800        // bf16[128][512]
#define WS_WHC     223872       // bf16[128][512] (combined heads)
#define WS_WSHT    354944       // bf16[512][512] (w_sh transposed)
#define WS_WSA     879232       // bf16[512][512]  (wsa|wra contiguous)
#define WS_WRA     1403520      // bf16[512][512]
#define WS_WCSA    1927808      // bf16[512][512] (w_sa@w_sh) (wcsa|wcra contiguous)
#define WS_WCRA    2452096      // bf16[512][512] (w_ra@w_sh)
#define WS_WCAT    2976384      // bf16[2048][576]
#define WS_XP      5335680      // bf16[32][1024][64]
#define WS_ES      9529984      // f32[32768]  (es|er contiguous)
#define WS_ER      9661056      // f32[32768]
#define WS_PROJ    9792128      // bf16[32768][64]
#define WS_HX      13986432     // bf16[1024][32][512]: slab t = h(t), row t*32+b

typedef __bf16  bf16x8 __attribute__((ext_vector_type(8)));
typedef float   f32x4  __attribute__((ext_vector_type(4)));
typedef uint4 uint4a __attribute__((may_alias));
typedef unsigned int u32;
typedef unsigned long long u64;

__device__ __forceinline__ float bf2f(unsigned short u) {
    unsigned int v = ((unsigned int)u) << 16;
    return __builtin_bit_cast(float, v);
}
__device__ __forceinline__ unsigned short f2bf(float f) {
    unsigned int u = __builtin_bit_cast(unsigned int, f);
    u += 0x7fffu + ((u >> 16) & 1u);          // round to nearest even
    return (unsigned short)(u >> 16);
}
__device__ __forceinline__ bf16x8 ldb8(const unsigned short* p) {
    uint4 v = *(const uint4a*)p;
    return __builtin_bit_cast(bf16x8, v);
}
__device__ __forceinline__ float sigf(float x) { return 1.f / (1.f + __expf(-x)); }
__device__ __forceinline__ float tanhfast(float x) { return 1.f - 2.f / (__expf(2.f * x) + 1.f); }

// dual-dtype raw-input loaders (fl: 1 = underlying buffer is fp32)
__device__ __forceinline__ unsigned short loadu(const void* p, int i, int fl) {
    return fl ? f2bf(((const float*)p)[i]) : ((const unsigned short*)p)[i];
}
__device__ __forceinline__ float loadf(const void* p, int i, int fl) {
    return fl ? ((const float*)p)[i] : bf2f(((const unsigned short*)p)[i]);
}

// ---------------------------------------------------------------------------
// dtype sniff
// ---------------------------------------------------------------------------
__global__ void sniff_k(const unsigned short* __restrict__ xr, unsigned int* __restrict__ flag) {
    if (threadIdx.x == 0) {
        int cnt = 0;
        for (int i = 0; i < 256; ++i) {
            unsigned short u = xr[i];
            int e = (u >> 7) & 0xFF;
            if (u == 0 || (e >= 100 && e <= 140)) ++cnt;
        }
        *flag = (cnt < 220) ? 1u : 0u;
    }
}

// ---------------------------------------------------------------------------
// elementwise conversions into ws pools
// ---------------------------------------------------------------------------
__global__ void prep_all(const void* x, const void* h0, const void* c0,
                         const void* w_sh, const void* w_sa, const void* w_ra,
                         const void* w_st, const void* w_rw,
                         const void* v_sa, const void* v_ra,
                         const void* b_sh, const void* bv_sa, const void* bv_ra,
                         char* ws) {
    const int fl = (int)*(const unsigned int*)(ws + WS_FLAG);
    unsigned short* xp    = (unsigned short*)(ws + WS_XP);
    unsigned short* h0s   = (unsigned short*)(ws + WS_H0);
    unsigned short* cp    = (unsigned short*)(ws + WS_CP);
    unsigned short* wshT  = (unsigned short*)(ws + WS_WSHT);
    unsigned short* wsa   = (unsigned short*)(ws + WS_WSA);
    unsigned short* wra   = (unsigned short*)(ws + WS_WRA);
    unsigned short* whpad = (unsigned short*)(ws + WS_WHPAD);
    unsigned short* vs    = (unsigned short*)(ws + WS_VS);
    unsigned short* vr    = (unsigned short*)(ws + WS_VR);
    float* bsh  = (float*)(ws + WS_BSH);
    float* scal = (float*)(ws + WS_SCAL);
    float* zb   = (float*)(ws + WS_ZB);

    int gt = blockIdx.x * 256 + threadIdx.x;
    int gs = gridDim.x * 256;
    for (int i = gt; i < BB * TT * II; i += gs) xp[i] = loadu(x, i, fl);
    for (int i = gt; i < BB * HH; i += gs) { h0s[i] = loadu(h0, i, fl); cp[i] = loadu(c0, i, fl); }
    for (int i = gt; i < HH * HH; i += gs) {
        int m = i >> 9, k = i & 511;
        // coalesced WRITE transpose: wshT[i] (i = k'*512 + m') reads
        // w_sh[m'*512 + k']; strided reads are absorbed by L2 (w_sh <= 1 MB).
        wshT[i] = loadu(w_sh, k * HH + m, fl);
        wsa[i] = loadu(w_sa, i, fl);
        wra[i] = loadu(w_ra, i, fl);
    }
    for (int i = gt; i < 128 * HH; i += gs) {
        int f = i >> 9, k = i & 511;
        whpad[i] = (f < FF) ? loadu(w_st, f * HH + k, fl)
                 : (f == FF ? loadu(w_rw, k, fl) : (unsigned short)0);
    }
    for (int i = gt; i < HH; i += gs) {
        vs[i] = loadu(v_sa, i, fl); vr[i] = loadu(v_ra, i, fl);
        bsh[i] = loadf(b_sh, i, fl); zb[i] = 0.f;
    }
    if (gt == 0) { scal[0] = loadf(bv_sa, 0, fl); scal[1] = loadf(bv_ra, 0, fl); }
}

__global__ void prep_w(const void* __restrict__ w_hh, const void* __restrict__ w_ih,
                       const void* __restrict__ b_ih, const void* __restrict__ b_hh,
                       char* ws) {
    const int fl = (int)*(const unsigned int*)(ws + WS_FLAG);
    unsigned short* wcat = (unsigned short*)(ws + WS_WCAT);
    float* biasc = (float*)(ws + WS_BIASC);
    int c = blockIdx.x;   // [0,2048)
    for (int k = threadIdx.x; k < KK; k += 256)
        wcat[c * KK + k] = (k < HH) ? loadu(w_hh, c * HH + k, fl)
                                    : loadu(w_ih, c * II + (k - HH), fl);
    if (threadIdx.x == 0) biasc[c] = loadf(b_ih, c, fl) + loadf(b_hh, c, fl);
}

// ---------------------------------------------------------------------------
// Persistent LSTM, single-XCD. 256 blocks; 32 on one XCD self-select as
// workers.  R7-proven skeleton (h ring via t-major hx; single poller wave0;
// LDS s_go release; acc chains 4x9; setprio; syncA; watchdog poison;
// loser blocks absorb the weight-combine GEMMs).
//
// R8: per-wave flag posts with PLAIN STORES to DISTINCT words:
//  - flag line of block g = 4 u32 words (one per wave).  Each wave drains
//    its own h-stores (s_waitcnt vmcnt 0 — the h-store data-depends on the
//    wave's gbuf reads, so those are complete too) and lane0 writes t+1
//    into its own word with a relaxed agent store.  No RMW -> no L2
//    serialization (R6's failure mode), no sync B barrier.
//  - wave0 polls each block line as two 64-bit relaxed loads; gate passes
//    when min of all 4 words >= t+1.  Release via LDS s_go as before.
//  - gbuf anti-dep chain: wave w's next-step gbuf writes happen after s_go
//    = t+1, set only after ALL 4 local words = t+1, each posted after that
//    wave's gbuf reads (data dependence through the h-store).  Sound.
// ---------------------------------------------------------------------------
__global__ __launch_bounds__(256, 1)
void lstm_k(char* __restrict__ ws, void* __restrict__ dout) {
    __shared__ float gbuf[32][68];
    __shared__ int s_slot;
    __shared__ u32 s_go;
    __shared__ unsigned short As2[128][72];   // loser-path GEMM staging
    __shared__ unsigned short Bs2[64][72];
    __shared__ int s_job;

    u32* tick   = (u32*)(ws + WS_TICK);
    u32* chosen = (u32*)(ws + WS_CHOSEN);

    // ---- XCD claim ----
    if (threadIdx.x == 0) {
        u32 xcc;
        asm volatile("s_getreg_b32 %0, hwreg(HW_REG_XCC_ID)" : "=s"(xcc));
        xcc &= 7u;
        int slot = -1;
        u32 tk = __hip_atomic_fetch_add(&tick[xcc], 1u, __ATOMIC_RELAXED,
                                        __HIP_MEMORY_SCOPE_AGENT);
        if (tk < (u32)NW) {
            if (tk == (u32)NW - 1u) {
                u32 expected = 0u;
                __hip_atomic_compare_exchange_strong(chosen, &expected, xcc + 1u,
                    __ATOMIC_RELAXED, __ATOMIC_RELAXED, __HIP_MEMORY_SCOPE_AGENT);
            }
            u32 c = 0u;
            for (int it = 0; it < (1 << 20); ++it) {
                c = __hip_atomic_load(chosen, __ATOMIC_RELAXED, __HIP_MEMORY_SCOPE_AGENT);
                if (c != 0u) break;
                __builtin_amdgcn_s_sleep(8);
            }
            if (c == xcc + 1u) slot = (int)tk;
        }
        s_slot = slot;
        s_go = 0u;
    }
    __syncthreads();
    const int g = s_slot;

    if (g < 0) {
        // ================= LOSER PATH: combine work on idle XCDs ==========
        const int tid = threadIdx.x;
        const int wave = tid >> 6, lane = tid & 63;
        const int quad = lane >> 4, l16 = lane & 15;
        const unsigned short* wshT = (const unsigned short*)(ws + WS_WSHT);
        const float* bsh = (const float*)(ws + WS_BSH);
        for (;;) {
            if (tid == 0)
                s_job = (int)__hip_atomic_fetch_add((u32*)(ws + WS_TICK2), 1u,
                            __ATOMIC_RELAXED, __HIP_MEMORY_SCOPE_AGENT);
            __syncthreads();
            const int job = s_job;
            if (job >= 75) return;
            if (job < 72) {
                // --- one 128x64 GEMM tile: C = A @ wshT^T (no bias) ---
                const int mb = (job < 64) ? (job >> 3) : 0;
                const int nb = (job < 64) ? (job & 7) : (job - 64);
                const unsigned short* A = (const unsigned short*)
                    (ws + ((job < 64) ? WS_WSA : WS_WHPAD));
                unsigned short* C = (unsigned short*)
                    (ws + ((job < 64) ? WS_WCSA : WS_WHC));
                f32x4 acc[2][4];
#pragma unroll
                for (int tm = 0; tm < 2; ++tm)
#pragma unroll
                    for (int tn = 0; tn < 4; ++tn) acc[tm][tn] = (f32x4){0.f, 0.f, 0.f, 0.f};
                for (int k0 = 0; k0 < 512; k0 += 64) {
#pragma unroll
                    for (int i = 0; i < 4; ++i) {
                        int v = tid + i * 256;
                        int rowa = v >> 3, kc = (v & 7) * 8;
                        *(uint4a*)&As2[rowa][kc] =
                            *(const uint4a*)(A + (mb * 128 + rowa) * 512 + k0 + kc);
                    }
#pragma unroll
                    for (int i = 0; i < 2; ++i) {
                        int v = tid + i * 256;
                        int rowb = v >> 3, kc = (v & 7) * 8;
                        *(uint4a*)&Bs2[rowb][kc] =
                            *(const uint4a*)(wshT + (nb * 64 + rowb) * 512 + k0 + kc);
                    }
                    __syncthreads();
#pragma unroll
                    for (int ks = 0; ks < 2; ++ks) {
                        bf16x8 a0 = ldb8(&As2[wave * 32 + l16][ks * 32 + quad * 8]);
                        bf16x8 a1 = ldb8(&As2[wave * 32 + 16 + l16][ks * 32 + quad * 8]);
#pragma unroll
                        for (int tn = 0; tn < 4; ++tn) {
                            bf16x8 bb = ldb8(&Bs2[tn * 16 + l16][ks * 32 + quad * 8]);
                            acc[0][tn] = __builtin_amdgcn_mfma_f32_16x16x32_bf16(a0, bb, acc[0][tn], 0, 0, 0);
                            acc[1][tn] = __builtin_amdgcn_mfma_f32_16x16x32_bf16(a1, bb, acc[1][tn], 0, 0, 0);
                        }
                    }
                    __syncthreads();
                }
#pragma unroll
                for (int tm = 0; tm < 2; ++tm)
#pragma unroll
                    for (int tn = 0; tn < 4; ++tn)
#pragma unroll
                        for (int r = 0; r < 4; ++r) {
                            int row = mb * 128 + wave * 32 + tm * 16 + quad * 4 + r;
                            int col = nb * 64 + tn * 16 + l16;
                            C[row * 512 + col] = f2bf(acc[tm][tn][r]);
                        }
            } else {
                // --- bias_comb core: bc[j] = sum_k W[j,k]*bsh[k] (raw bias
                //     added later by bias_fix) ---
                if (job == 72 || job == 73) {
                    const unsigned short* w = (const unsigned short*)
                        (ws + ((job == 72) ? WS_WSA : WS_WRA));
                    float* o = (float*)(ws + ((job == 72) ? WS_BCSA : WS_BCRA));
                    for (int j = tid; j < 512; j += 256) {
                        float s = 0.f;
                        for (int k = 0; k < HH; ++k) s += bf2f(w[j * HH + k]) * bsh[k];
                        o[j] = s;
                    }
                } else {
                    const unsigned short* w = (const unsigned short*)(ws + WS_WHPAD);
                    float* o = (float*)(ws + WS_BCH);
                    if (tid < 64) {
                        float s = 0.f;
                        for (int k = 0; k < HH; ++k) s += bf2f(w[tid * HH + k]) * bsh[k];
                        o[tid] = s;
                    }
                }
            }
            __syncthreads();    // protect s_job / LDS reuse across jobs
        }
        // (unreachable)
    }

    // ================= WINNER PATH =====================
    const unsigned short* xp    = (const unsigned short*)(ws + WS_XP);
    const unsigned short* wcat  = (const unsigned short*)(ws + WS_WCAT);
    const float*          biasc = (const float*)(ws + WS_BIASC);
    const unsigned short* cinit = (const unsigned short*)(ws + WS_CP);
    const unsigned short* h0s   = (const unsigned short*)(ws + WS_H0);
    unsigned short*       hx    = (unsigned short*)(ws + WS_HX);
    u32*                  flags = (u32*)(ws + WS_FLAGS);
    const int fl = (int)*(const unsigned int*)(ws + WS_FLAG);

    const int tid  = threadIdx.x;
    const int wave = tid >> 6, lane = tid & 63;
    const int quad = lane >> 4, l16 = lane & 15;
    const int mh = wave & 1, nh = wave >> 1;
    const int m = mh * 16 + l16;   // batch row for A frags

    // resident weight fragments: 2 n-tiles x 18 k-steps
    bf16x8 bw[2][18];
#pragma unroll
    for (int tn = 0; tn < 2; ++tn) {
        int nl   = nh * 32 + tn * 16 + l16;                 // local col [0,64)
        int gcol = (nl >> 4) * HH + g * 16 + (nl & 15);     // global gate col
        const unsigned short* wp = wcat + gcol * KK + quad * 8;
#pragma unroll
        for (int ks = 0; ks < 18; ++ks) bw[tn][ks] = ldb8(wp + ks * 32);
    }

    // epilogue: thread -> batch b, cell pair (cc, cc+1)
    const int b  = tid >> 3, pr = tid & 7, cc = pr * 2;
    const int n  = g * 16 + cc;                 // even global cell index
    const float bi0 = biasc[n],          bi1 = biasc[n + 1];
    const float bff0 = biasc[HH + n],    bff1 = biasc[HH + n + 1];
    const float bg0 = biasc[2*HH + n],   bg1 = biasc[2*HH + n + 1];
    const float bo0 = biasc[3*HH + n],   bo1 = biasc[3*HH + n + 1];
    float cst0 = bf2f(cinit[b * HH + n]);
    float cst1 = bf2f(cinit[b * HH + n + 1]);

    const unsigned short* xbase = xp + m * (TT * II) + quad * 8;
    bf16x8 ax0 = ldb8(xbase), ax1 = ldb8(xbase + 32);

    u32* myflag = flags + g * 32;               // own 128-B flag line (4 words)
    u32* pollp  = flags + (lane & 31) * 32;     // lane j -> block j's line

    for (int t = 0; t < TT; ++t) {
        // x prefetch for t+1 issued first
        int tn1 = (t + 1 < TT) ? t + 1 : t;
        bf16x8 axn0 = ldb8(xbase + tn1 * II);
        bf16x8 axn1 = ldb8(xbase + tn1 * II + 32);

        // ---- A-frags for h(t-1): plain loads (fresh addresses -> L1 miss
        //      -> probe of the XCD's shared L2 which holds the stores) ----
        const unsigned short* hrow =
            (t == 0 ? h0s : hx + (t - 1) * (BB * HH)) + m * HH + quad * 8;
        bf16x8 a[16];
#pragma unroll
        for (int i = 0; i < 16; ++i) a[i] = ldb8(hrow + i * 32);

        // 4 independent 9-deep MFMA chains; x-terms first so they issue
        // while the h-loads are still in flight.
        f32x4 acc0  = {0.f, 0.f, 0.f, 0.f}, acc1  = {0.f, 0.f, 0.f, 0.f};
        f32x4 acc0b = {0.f, 0.f, 0.f, 0.f}, acc1b = {0.f, 0.f, 0.f, 0.f};
        __builtin_amdgcn_s_setprio(1);
        acc0  = __builtin_amdgcn_mfma_f32_16x16x32_bf16(ax0, bw[0][16], acc0,  0, 0, 0);
        acc1  = __builtin_amdgcn_mfma_f32_16x16x32_bf16(ax0, bw[1][16], acc1,  0, 0, 0);
        acc0b = __builtin_amdgcn_mfma_f32_16x16x32_bf16(ax1, bw[0][17], acc0b, 0, 0, 0);
        acc1b = __builtin_amdgcn_mfma_f32_16x16x32_bf16(ax1, bw[1][17], acc1b, 0, 0, 0);
#pragma unroll
        for (int i = 0; i < 8; ++i) {
            acc0  = __builtin_amdgcn_mfma_f32_16x16x32_bf16(a[i],     bw[0][i],     acc0,  0, 0, 0);
            acc1  = __builtin_amdgcn_mfma_f32_16x16x32_bf16(a[i],     bw[1][i],     acc1,  0, 0, 0);
            acc0b = __builtin_amdgcn_mfma_f32_16x16x32_bf16(a[i + 8], bw[0][i + 8], acc0b, 0, 0, 0);
            acc1b = __builtin_amdgcn_mfma_f32_16x16x32_bf16(a[i + 8], bw[1][i + 8], acc1b, 0, 0, 0);
        }
        __builtin_amdgcn_s_setprio(0);
        acc0 = acc0 + acc0b;
        acc1 = acc1 + acc1b;

        // ---- C-frag -> LDS (row = batch, col = quad*16 + local cell) ----
        {
            int row = mh * 16 + quad * 4;
#pragma unroll
            for (int r = 0; r < 4; ++r) gbuf[row + r][nh * 32 + l16]      = acc0[r];
#pragma unroll
            for (int r = 0; r < 4; ++r) gbuf[row + r][nh * 32 + 16 + l16] = acc1[r];
        }
        __syncthreads();    // sync A: gbuf ready

        // ---- epilogue: 2 adjacent cells per thread, one u32 h-store ----
        {
            float2 giv = *(const float2*)&gbuf[b][cc];
            float2 gfv = *(const float2*)&gbuf[b][16 + cc];
            float2 ggv = *(const float2*)&gbuf[b][32 + cc];
            float2 gov = *(const float2*)&gbuf[b][48 + cc];
            cst0 = sigf(gfv.x + bff0) * cst0 + sigf(giv.x + bi0) * tanhfast(ggv.x + bg0);
            cst1 = sigf(gfv.y + bff1) * cst1 + sigf(giv.y + bi1) * tanhfast(ggv.y + bg1);
            float h0v = sigf(gov.x + bo0) * tanhfast(cst0);
            float h1v = sigf(gov.y + bo1) * tanhfast(cst1);
            u32 hp = (u32)f2bf(h0v) | ((u32)f2bf(h1v) << 16);
            *(u32*)&hx[t * (BB * HH) + b * HH + n] = hp;   // h(t) -> slab t
            if (t == TT - 1) {
                if (fl) {
                    ((float*)dout)[HT_OFF + b * HH + n]     = h0v;
                    ((float*)dout)[HT_OFF + b * HH + n + 1] = h1v;
                    ((float*)dout)[CT_OFF + b * HH + n]     = cst0;
                    ((float*)dout)[CT_OFF + b * HH + n + 1] = cst1;
                } else {
                    ((u32*)dout)[(HT_OFF + b * HH + n) >> 1] = hp;
                    ((u32*)dout)[(CT_OFF + b * HH + n) >> 1] =
                        (u32)f2bf(cst0) | ((u32)f2bf(cst1) << 16);
                }
            }
        }

        // ---- per-wave post: drain own VMEM (h-stores acked in L2; gbuf
        //      reads complete by data dependence), then write own flag
        //      word with a plain relaxed agent store.  NO sync B. ----
        asm volatile("s_waitcnt vmcnt(0)" ::: "memory");
        if (lane == 0)
            __hip_atomic_store(myflag + wave, (u32)(t + 1), __ATOMIC_RELAXED,
                               __HIP_MEMORY_SCOPE_AGENT);

        // ---- wave 0 polls all 32 lines (2 x 64-bit loads each, min of 4
        //      words); releases siblings through LDS s_go.  Values:
        //      t+1 = go, TT+2 = poison. ----
        u32 die = 0u;
        if (wave == 0) {
            const u32 tgt = (u32)(t + 1);
            int it = 0;
            for (;;) {
                u32 mn = tgt;
                if (lane < 32) {
                    const u64* p64 = (const u64*)pollp;
                    u64 v01 = __hip_atomic_load(p64,     __ATOMIC_RELAXED, __HIP_MEMORY_SCOPE_AGENT);
                    u64 v23 = __hip_atomic_load(p64 + 1, __ATOMIC_RELAXED, __HIP_MEMORY_SCOPE_AGENT);
                    u32 a0 = (u32)v01, a1 = (u32)(v01 >> 32);
                    u32 a2 = (u32)v23, a3 = (u32)(v23 >> 32);
                    u32 m01 = a0 < a1 ? a0 : a1;
                    u32 m23 = a2 < a3 ? a2 : a3;
                    mn = m01 < m23 ? m01 : m23;
                }
                if (__all((int)(mn >= tgt))) break;
                if (++it > (1 << 17)) { die = 1u; break; }   // watchdog
            }
            if (lane == 0) {
                if (die) {
#pragma unroll
                    for (int w2 = 0; w2 < 4; ++w2)   // free peers: poison line
                        __hip_atomic_store(myflag + w2, (u32)(TT + 2),
                                           __ATOMIC_RELAXED, __HIP_MEMORY_SCOPE_AGENT);
                }
                __hip_atomic_store(&s_go, die ? (u32)(TT + 2) : (u32)(t + 1),
                                   __ATOMIC_RELAXED, __HIP_MEMORY_SCOPE_WORKGROUP);
            }
        } else {
            const u32 tgt = (u32)(t + 1);
            int it = 0; u32 v;
            for (;;) {
                v = __hip_atomic_load(&s_go, __ATOMIC_RELAXED,
                                      __HIP_MEMORY_SCOPE_WORKGROUP);
                if (v >= tgt) break;
                if (++it > (1 << 21)) { v = (u32)(TT + 2); break; }  // bounded
            }
            if (v >= (u32)(TT + 1)) die = 1u;   // poison (normal max is TT)
        }
        if (die) break;     // wave-uniform; fail fast, never hang
        asm volatile("" ::: "memory");
        ax0 = axn0; ax1 = axn1;                 // rotate x prefetch
    }
}

// ---------------------------------------------------------------------------
// raw-bias add fixup for the combined biases computed inside lstm_k's loser
// path (they hold only W@b_sh; add b_sa/b_ra/b_st/b_rw here, dtype-aware).
// ---------------------------------------------------------------------------
__global__ void bias_fix(const void* b_sa, const void* b_ra,
                         const void* b_st, const void* b_rw, char* ws) {
    const int fl = (int)*(const unsigned int*)(ws + WS_FLAG);
    int j = threadIdx.x;                 // 512 threads
    if (blockIdx.x == 0)      ((float*)(ws + WS_BCSA))[j] += loadf(b_sa, j, fl);
    else if (blockIdx.x == 1) ((float*)(ws + WS_BCRA))[j] += loadf(b_ra, j, fl);
    else if (j < 64)
        ((float*)(ws + WS_BCH))[j] += (j < FF) ? loadf(b_st, j, fl) : loadf(b_rw, 0, fl);
}

// ---------------------------------------------------------------------------
// Fused tail GEMM over A = routs [MM x 512] (t-major hx ring).
// grid (17, 256): blockIdx.x = nb (FASTEST -> consecutive blocks share the
// same A-tile -> XCD L2 reuse), blockIdx.y = mb.
//   nb 0..7  : W = wcsa rows, e-epilogue -> atomicAdd(es[row], .)
//   nb 8..15 : W = wcra rows (stacked contiguously), -> atomicAdd(er[row], .)
//   nb == 16 : W = whc rows 0..63, bf16 write proj[row*64+col] + bch bias
// ---------------------------------------------------------------------------
__global__ __launch_bounds__(256)
void gemm_tail(const unsigned short* __restrict__ A,
               const unsigned short* __restrict__ Wes,   // wcsa (wcsa|wcra stacked, 1024 rows)
               const float* __restrict__ bes,            // bcsa|bcra f32[1024]
               const unsigned short* __restrict__ vvs,   // vs|vr bf16[1024]
               float* __restrict__ eout,                 // es|er f32[2*MM]
               const unsigned short* __restrict__ Wpj,   // whc
               const float* __restrict__ bpj,            // bch f32[64]
               unsigned short* __restrict__ proj) {
    __shared__ unsigned short As[128][72];
    __shared__ unsigned short Bs[64][72];
    const int tid = threadIdx.x;
    const int wave = tid >> 6, lane = tid & 63, quad = lane >> 4, l16 = lane & 15;
    const int nb = blockIdx.x, mb = blockIdx.y;
    const bool ispj = (nb == 16);
    const unsigned short* W = ispj ? Wpj : (Wes + nb * 64 * 512);

    f32x4 acc[2][4];
#pragma unroll
    for (int tm = 0; tm < 2; ++tm)
#pragma unroll
        for (int tn = 0; tn < 4; ++tn) acc[tm][tn] = (f32x4){0.f, 0.f, 0.f, 0.f};

    for (int k0 = 0; k0 < 512; k0 += 64) {
#pragma unroll
        for (int i = 0; i < 4; ++i) {
            int v = tid + i * 256;
            int rowa = v >> 3, kc = (v & 7) * 8;
            *(uint4a*)&As[rowa][kc] = *(const uint4a*)(A + (mb * 128 + rowa) * 512 + k0 + kc);
        }
#pragma unroll
        for (int i = 0; i < 2; ++i) {
            int v = tid + i * 256;
            int rowb = v >> 3, kc = (v & 7) * 8;
            *(uint4a*)&Bs[rowb][kc] = *(const uint4a*)(W + rowb * 512 + k0 + kc);
        }
        __syncthreads();
#pragma unroll
        for (int ks = 0; ks < 2; ++ks) {
            bf16x8 a0 = ldb8(&As[wave * 32 + l16][ks * 32 + quad * 8]);
            bf16x8 a1 = ldb8(&As[wave * 32 + 16 + l16][ks * 32 + quad * 8]);
#pragma unroll
            for (int tn = 0; tn < 4; ++tn) {
                bf16x8 bb = ldb8(&Bs[tn * 16 + l16][ks * 32 + quad * 8]);
                acc[0][tn] = __builtin_amdgcn_mfma_f32_16x16x32_bf16(a0, bb, acc[0][tn], 0, 0, 0);
                acc[1][tn] = __builtin_amdgcn_mfma_f32_16x16x32_bf16(a1, bb, acc[1][tn], 0, 0, 0);
            }
        }
        __syncthreads();
    }
    if (ispj) {
#pragma unroll
        for (int tm = 0; tm < 2; ++tm)
#pragma unroll
            for (int tn = 0; tn < 4; ++tn)
#pragma unroll
                for (int r = 0; r < 4; ++r) {
                    int row = mb * 128 + wave * 32 + tm * 16 + quad * 4 + r;
                    int col = tn * 16 + l16;
                    proj[row * 64 + col] = f2bf(acc[tm][tn][r] + bpj[col]);
                }
    } else {
        const int eoff = (nb >= 8) ? MM : 0;    // es | er (contiguous)
        float vcol[4], bcol[4];
#pragma unroll
        for (int tn = 0; tn < 4; ++tn) {
            int col = nb * 64 + tn * 16 + l16;
            vcol[tn] = bf2f(vvs[col]); bcol[tn] = bes[col];
        }
#pragma unroll
        for (int tm = 0; tm < 2; ++tm)
#pragma unroll
            for (int r = 0; r < 4; ++r) {
                float s = 0.f;
#pragma unroll
                for (int tn = 0; tn < 4; ++tn)
                    s += vcol[tn] * tanhfast(acc[tm][tn][r] + bcol[tn]);
                s += __shfl_xor(s, 1); s += __shfl_xor(s, 2);
                s += __shfl_xor(s, 4); s += __shfl_xor(s, 8);
                if (l16 == 0) {
                    int row = mb * 128 + wave * 32 + tm * 16 + quad * 4 + r;
                    atomicAdd(&eout[eoff + row], s);
                }
            }
    }
}

// ---------------------------------------------------------------------------
// Online-softmax cumulative scan, software-pipelined.
// Reads row index t*32+b (t-major); writes original (b,t) layout.
// bv_sa / bv_ra are folded in HERE (es/er are zero-initialized + atomics).
// ---------------------------------------------------------------------------
__global__ __launch_bounds__(64)
void cumsum_k(char* __restrict__ ws, void* __restrict__ dout) {
    const unsigned short* proj = (const unsigned short*)(ws + WS_PROJ);
    const float* es = (const float*)(ws + WS_ES);
    const float* er = (const float*)(ws + WS_ER);
    const float* scal = (const float*)(ws + WS_SCAL);
    const int fl = (int)*(const unsigned int*)(ws + WS_FLAG);
    const int b = blockIdx.x, lane = threadIdx.x;
    const bool isr = (lane == 63);
    const float bv = isr ? scal[1] : scal[0];
    float m_ = -3e38f, d_ = 0.f, n_ = 0.f;
    float pj = bf2f(proj[b * 64 + lane]);       // row t=0 -> index b
    float e  = (isr ? er[b] : es[b]) + bv;
    for (int t = 0; t < TT; ++t) {
        float pjn = 0.f, en = 0.f;
        if (t + 1 < TT) {                       // prefetch next row (t+1)*32+b
            int rn = (t + 1) * BB + b;
            pjn = bf2f(proj[rn * 64 + lane]);
            en  = (isr ? er[rn] : es[rn]) + bv;
        }
        float mn = fmaxf(m_, e);
        float al = __expf(m_ - mn);
        float p  = __expf(e - mn);
        d_ = d_ * al + p;
        n_ = n_ * al + p * pj;
        m_ = mn;
        float o = n_ / d_;
        int rout = b * TT + t;
        int addr = isr ? (RW_OFF + rout) : (rout * FF + lane);
        if (fl) ((float*)dout)[addr] = o;
        else    ((unsigned short*)dout)[addr] = f2bf(o);
        pj = pjn; e = en;
    }
}

// ---------------------------------------------------------------------------
extern "C" void kernel_launch(void* const* d_in, const int* in_sizes, int n_in,
                              void* d_out, int out_size, void* d_ws, size_t ws_size,
                              hipStream_t stream) {
    const void* x    = d_in[0];
    const void* h0   = d_in[2];
    const void* c0   = d_in[3];
    const void* w_ih = d_in[4];
    const void* w_hh = d_in[5];
    const void* b_ih = d_in[6];
    const void* b_hh = d_in[7];
    const void* w_sh = d_in[8];
    const void* b_sh = d_in[9];
    const void* w_sa = d_in[10];
    const void* b_sa = d_in[11];
    const void* v_sa = d_in[12];
    const void* bv_sa= d_in[13];
    const void* w_ra = d_in[14];
    const void* b_ra = d_in[15];
    const void* v_ra = d_in[16];
    const void* bv_ra= d_in[17];
    const void* w_st = d_in[18];
    const void* b_st = d_in[19];
    const void* w_rw = d_in[20];
    const void* b_rw = d_in[21];

    char* ws = (char*)d_ws;
    unsigned short* wcsa  = (unsigned short*)(ws + WS_WCSA);
    unsigned short* whc   = (unsigned short*)(ws + WS_WHC);
    unsigned short* routs = (unsigned short*)(ws + WS_HX);   // t-major h ring
    unsigned short* proj  = (unsigned short*)(ws + WS_PROJ);
    unsigned short* vs    = (unsigned short*)(ws + WS_VS);
    float* bcsa = (float*)(ws + WS_BCSA);
    float* bch  = (float*)(ws + WS_BCH);
    float* es   = (float*)(ws + WS_ES);

    (void)hipMemsetAsync(d_ws, 0, 8448, stream);             // flags + dtype + tick/chosen + tick2
    (void)hipMemsetAsync(ws + WS_ES, 0, 2 * MM * 4, stream); // es|er accumulators
    sniff_k<<<1, 64, 0, stream>>>((const unsigned short*)x, (unsigned int*)(ws + WS_FLAG));
    prep_all<<<1024, 256, 0, stream>>>(x, h0, c0, w_sh, w_sa, w_ra, w_st, w_rw,
                                       v_sa, v_ra, b_sh, bv_sa, bv_ra, ws);
    prep_w<<<G4H, 256, 0, stream>>>(w_hh, w_ih, b_ih, b_hh, ws);

    // sequential LSTM: 32 winner blocks on one XCD; 224 losers absorb the
    // weight-combine GEMMs + bias combines in parallel on the idle XCDs.
    lstm_k<<<256, 256, 0, stream>>>(ws, d_out);

    // add raw biases to the loser-computed combined biases (cheap fixup)
    bias_fix<<<3, 512, 0, stream>>>(b_sa, b_ra, b_st, b_rw, ws);

    // fused tail: e_s, e_r AND proj in one pass over A (nb fastest for L2 reuse)
    gemm_tail<<<dim3(17, 256), 256, 0, stream>>>(routs, wcsa, bcsa, vs, es,
                                                 whc, bch, proj);
    // online-softmax causal scan -> state_outs + reward_outs
    cumsum_k<<<BB, 64, 0, stream>>>(ws, d_out);
}

// Round 9
// 4005.983 us; speedup vs baseline: 1.1143x; 1.1143x over previous
//
#include <hip/hip_runtime.h>

// ---------------------------------------------------------------------------
// Sizes
// ---------------------------------------------------------------------------
#define BB 32
#define TT 1024
#define II 64
#define HH 512
#define FF 63
#define G4H 2048         // 4*H
#define KK 576           // H + I (concat [h | x])
#define MM 32768         // B*T
#define NW 32            // worker blocks (each owns 16 cells)

// out layout (elements): state[B,T,63] | reward[B,T] | hT[B,H] | cT[B,H]
#define RW_OFF 2064384
#define HT_OFF 2097152
#define CT_OFF 2113536

// ws layout (bytes)
#define WS_FLAGS   0            // u32[NW] @128-B stride: per-worker step counts
#define WS_FLAG    4096         // u32 (1 = inputs are fp32)
#define WS_TICK    4224         // u32[8] per-XCD ticket counters
#define WS_CHOSEN  4288         // u32: 0 = undecided, else winning xcc+1
#define WS_TICK2   4352         // u32: loser-block job ticket (combine work)
#define WS_BIASC   8448         // f32[2048]
#define WS_BSH     16640        // f32[512]
#define WS_BCSA    18688        // f32[512]   (bcsa|bcra contiguous)
#define WS_BCRA    20736        // f32[512]
#define WS_BCH     22784        // f32[64]
#define WS_SCAL    23040        // f32[2]: bv_sa, bv_ra
#define WS_VS      23168        // bf16[512]  (vs|vr contiguous)
#define WS_VR      24192        // bf16[512]
#define WS_ZB      25216        // f32[512] zeros
#define WS_H0      27264        // bf16[32][512]  (h0 slab)
#define WS_CP      60032        // bf16[32][512] (c0 converted)
#define WS_WHPAD   92800        // bf16[128][512]
#define WS_WHC     223872       // bf16[128][512] (combined heads)
#define WS_WSHT    354944       // bf16[512][512] (w_sh transposed)
#define WS_WSA     879232       // bf16[512][512]  (wsa|wra contiguous)
#define WS_WRA     1403520      // bf16[512][512]
#define WS_WCSA    1927808      // bf16[512][512] (w_sa@w_sh) (wcsa|wcra contiguous)
#define WS_WCRA    2452096      // bf16[512][512] (w_ra@w_sh)
#define WS_WCAT    2976384      // bf16[2048][576]
#define WS_XP      5335680      // bf16[32][1024][64]
#define WS_ES      9529984      // f32[32768]  (es|er contiguous)
#define WS_ER      9661056      // f32[32768]
#define WS_PROJ    9792128      // bf16[32768][64]
#define WS_HX      13986432     // bf16[1024][32][512]: slab t = h(t), row t*32+b

typedef __bf16  bf16x8 __attribute__((ext_vector_type(8)));
typedef float   f32x4  __attribute__((ext_vector_type(4)));
typedef uint4 uint4a __attribute__((may_alias));
typedef unsigned int u32;

__device__ __forceinline__ float bf2f(unsigned short u) {
    unsigned int v = ((unsigned int)u) << 16;
    return __builtin_bit_cast(float, v);
}
__device__ __forceinline__ unsigned short f2bf(float f) {
    unsigned int u = __builtin_bit_cast(unsigned int, f);
    u += 0x7fffu + ((u >> 16) & 1u);          // round to nearest even
    return (unsigned short)(u >> 16);
}
__device__ __forceinline__ bf16x8 ldb8(const unsigned short* p) {
    uint4 v = *(const uint4a*)p;
    return __builtin_bit_cast(bf16x8, v);
}
__device__ __forceinline__ float sigf(float x) { return 1.f / (1.f + __expf(-x)); }
__device__ __forceinline__ float tanhfast(float x) { return 1.f - 2.f / (__expf(2.f * x) + 1.f); }

// dual-dtype raw-input loaders (fl: 1 = underlying buffer is fp32)
__device__ __forceinline__ unsigned short loadu(const void* p, int i, int fl) {
    return fl ? f2bf(((const float*)p)[i]) : ((const unsigned short*)p)[i];
}
__device__ __forceinline__ float loadf(const void* p, int i, int fl) {
    return fl ? ((const float*)p)[i] : bf2f(((const unsigned short*)p)[i]);
}

// ---------------------------------------------------------------------------
// dtype sniff
// ---------------------------------------------------------------------------
__global__ void sniff_k(const unsigned short* __restrict__ xr, unsigned int* __restrict__ flag) {
    if (threadIdx.x == 0) {
        int cnt = 0;
        for (int i = 0; i < 256; ++i) {
            unsigned short u = xr[i];
            int e = (u >> 7) & 0xFF;
            if (u == 0 || (e >= 100 && e <= 140)) ++cnt;
        }
        *flag = (cnt < 220) ? 1u : 0u;
    }
}

// ---------------------------------------------------------------------------
// elementwise conversions into ws pools
// ---------------------------------------------------------------------------
__global__ void prep_all(const void* x, const void* h0, const void* c0,
                         const void* w_sh, const void* w_sa, const void* w_ra,
                         const void* w_st, const void* w_rw,
                         const void* v_sa, const void* v_ra,
                         const void* b_sh, const void* bv_sa, const void* bv_ra,
                         char* ws) {
    const int fl = (int)*(const unsigned int*)(ws + WS_FLAG);
    unsigned short* xp    = (unsigned short*)(ws + WS_XP);
    unsigned short* h0s   = (unsigned short*)(ws + WS_H0);
    unsigned short* cp    = (unsigned short*)(ws + WS_CP);
    unsigned short* wshT  = (unsigned short*)(ws + WS_WSHT);
    unsigned short* wsa   = (unsigned short*)(ws + WS_WSA);
    unsigned short* wra   = (unsigned short*)(ws + WS_WRA);
    unsigned short* whpad = (unsigned short*)(ws + WS_WHPAD);
    unsigned short* vs    = (unsigned short*)(ws + WS_VS);
    unsigned short* vr    = (unsigned short*)(ws + WS_VR);
    float* bsh  = (float*)(ws + WS_BSH);
    float* scal = (float*)(ws + WS_SCAL);
    float* zb   = (float*)(ws + WS_ZB);

    int gt = blockIdx.x * 256 + threadIdx.x;
    int gs = gridDim.x * 256;
    for (int i = gt; i < BB * TT * II; i += gs) xp[i] = loadu(x, i, fl);
    for (int i = gt; i < BB * HH; i += gs) { h0s[i] = loadu(h0, i, fl); cp[i] = loadu(c0, i, fl); }
    for (int i = gt; i < HH * HH; i += gs) {
        int m = i >> 9, k = i & 511;
        // coalesced WRITE transpose: wshT[i] (i = k'*512 + m') reads
        // w_sh[m'*512 + k']; strided reads are absorbed by L2 (w_sh <= 1 MB).
        wshT[i] = loadu(w_sh, k * HH + m, fl);
        wsa[i] = loadu(w_sa, i, fl);
        wra[i] = loadu(w_ra, i, fl);
    }
    for (int i = gt; i < 128 * HH; i += gs) {
        int f = i >> 9, k = i & 511;
        whpad[i] = (f < FF) ? loadu(w_st, f * HH + k, fl)
                 : (f == FF ? loadu(w_rw, k, fl) : (unsigned short)0);
    }
    for (int i = gt; i < HH; i += gs) {
        vs[i] = loadu(v_sa, i, fl); vr[i] = loadu(v_ra, i, fl);
        bsh[i] = loadf(b_sh, i, fl); zb[i] = 0.f;
    }
    if (gt == 0) { scal[0] = loadf(bv_sa, 0, fl); scal[1] = loadf(bv_ra, 0, fl); }
}

__global__ void prep_w(const void* __restrict__ w_hh, const void* __restrict__ w_ih,
                       const void* __restrict__ b_ih, const void* __restrict__ b_hh,
                       char* ws) {
    const int fl = (int)*(const unsigned int*)(ws + WS_FLAG);
    unsigned short* wcat = (unsigned short*)(ws + WS_WCAT);
    float* biasc = (float*)(ws + WS_BIASC);
    int c = blockIdx.x;   // [0,2048)
    for (int k = threadIdx.x; k < KK; k += 256)
        wcat[c * KK + k] = (k < HH) ? loadu(w_hh, c * HH + k, fl)
                                    : loadu(w_ih, c * II + (k - HH), fl);
    if (threadIdx.x == 0) biasc[c] = loadf(b_ih, c, fl) + loadf(b_hh, c, fl);
}

// ---------------------------------------------------------------------------
// Persistent LSTM, single-XCD. 256 blocks; 32 on one XCD self-select as
// workers.  R7-proven protocol, byte-identical winner path (h ring via
// t-major hx; ONE flag RMW per block per step posted after sync B; wave0
// polls 32 lines sc1; LDS s_go release; acc chains 4x9; setprio; syncA +
// syncB; watchdog poison).  R8's per-wave posts REGRESSED (same-line
// store serialization + lost wave co-scheduling) — reverted.
//
// Loser blocks (224) ticket jobs from WS_TICK2 and compute the weight
// combines in PARALLEL with the LSTM on idle XCDs:
//   jobs 0..63 : 128x64 tile (mb=j>>3, nb=j&7) of [wsa|wra] @ wshT^T
//   jobs 64..71: 128x64 tile (mb=0, nb=j-64) of whpad @ wshT^T -> whc
//   jobs 72..74: bias_comb cores (W @ b_sh; raw bias added by bias_fix)
// No inter-block waits in the loser path (cannot hang).
// ---------------------------------------------------------------------------
__global__ __launch_bounds__(256, 1)
void lstm_k(char* __restrict__ ws, void* __restrict__ dout) {
    __shared__ float gbuf[32][68];
    __shared__ int s_slot;
    __shared__ u32 s_go;
    __shared__ unsigned short As2[128][72];   // loser-path GEMM staging
    __shared__ unsigned short Bs2[64][72];
    __shared__ int s_job;

    u32* tick   = (u32*)(ws + WS_TICK);
    u32* chosen = (u32*)(ws + WS_CHOSEN);

    // ---- XCD claim ----
    if (threadIdx.x == 0) {
        u32 xcc;
        asm volatile("s_getreg_b32 %0, hwreg(HW_REG_XCC_ID)" : "=s"(xcc));
        xcc &= 7u;
        int slot = -1;
        u32 tk = __hip_atomic_fetch_add(&tick[xcc], 1u, __ATOMIC_RELAXED,
                                        __HIP_MEMORY_SCOPE_AGENT);
        if (tk < (u32)NW) {
            if (tk == (u32)NW - 1u) {
                u32 expected = 0u;
                __hip_atomic_compare_exchange_strong(chosen, &expected, xcc + 1u,
                    __ATOMIC_RELAXED, __ATOMIC_RELAXED, __HIP_MEMORY_SCOPE_AGENT);
            }
            u32 c = 0u;
            for (int it = 0; it < (1 << 20); ++it) {
                c = __hip_atomic_load(chosen, __ATOMIC_RELAXED, __HIP_MEMORY_SCOPE_AGENT);
                if (c != 0u) break;
                __builtin_amdgcn_s_sleep(8);
            }
            if (c == xcc + 1u) slot = (int)tk;
        }
        s_slot = slot;
        s_go = 0u;
    }
    __syncthreads();
    const int g = s_slot;

    if (g < 0) {
        // ================= LOSER PATH: combine work on idle XCDs ==========
        const int tid = threadIdx.x;
        const int wave = tid >> 6, lane = tid & 63;
        const int quad = lane >> 4, l16 = lane & 15;
        const unsigned short* wshT = (const unsigned short*)(ws + WS_WSHT);
        const float* bsh = (const float*)(ws + WS_BSH);
        for (;;) {
            if (tid == 0)
                s_job = (int)__hip_atomic_fetch_add((u32*)(ws + WS_TICK2), 1u,
                            __ATOMIC_RELAXED, __HIP_MEMORY_SCOPE_AGENT);
            __syncthreads();
            const int job = s_job;
            if (job >= 75) return;
            if (job < 72) {
                // --- one 128x64 GEMM tile: C = A @ wshT^T (no bias) ---
                const int mb = (job < 64) ? (job >> 3) : 0;
                const int nb = (job < 64) ? (job & 7) : (job - 64);
                const unsigned short* A = (const unsigned short*)
                    (ws + ((job < 64) ? WS_WSA : WS_WHPAD));
                unsigned short* C = (unsigned short*)
                    (ws + ((job < 64) ? WS_WCSA : WS_WHC));
                f32x4 acc[2][4];
#pragma unroll
                for (int tm = 0; tm < 2; ++tm)
#pragma unroll
                    for (int tn = 0; tn < 4; ++tn) acc[tm][tn] = (f32x4){0.f, 0.f, 0.f, 0.f};
                for (int k0 = 0; k0 < 512; k0 += 64) {
#pragma unroll
                    for (int i = 0; i < 4; ++i) {
                        int v = tid + i * 256;
                        int rowa = v >> 3, kc = (v & 7) * 8;
                        *(uint4a*)&As2[rowa][kc] =
                            *(const uint4a*)(A + (mb * 128 + rowa) * 512 + k0 + kc);
                    }
#pragma unroll
                    for (int i = 0; i < 2; ++i) {
                        int v = tid + i * 256;
                        int rowb = v >> 3, kc = (v & 7) * 8;
                        *(uint4a*)&Bs2[rowb][kc] =
                            *(const uint4a*)(wshT + (nb * 64 + rowb) * 512 + k0 + kc);
                    }
                    __syncthreads();
#pragma unroll
                    for (int ks = 0; ks < 2; ++ks) {
                        bf16x8 a0 = ldb8(&As2[wave * 32 + l16][ks * 32 + quad * 8]);
                        bf16x8 a1 = ldb8(&As2[wave * 32 + 16 + l16][ks * 32 + quad * 8]);
#pragma unroll
                        for (int tn = 0; tn < 4; ++tn) {
                            bf16x8 bb = ldb8(&Bs2[tn * 16 + l16][ks * 32 + quad * 8]);
                            acc[0][tn] = __builtin_amdgcn_mfma_f32_16x16x32_bf16(a0, bb, acc[0][tn], 0, 0, 0);
                            acc[1][tn] = __builtin_amdgcn_mfma_f32_16x16x32_bf16(a1, bb, acc[1][tn], 0, 0, 0);
                        }
                    }
                    __syncthreads();
                }
#pragma unroll
                for (int tm = 0; tm < 2; ++tm)
#pragma unroll
                    for (int tn = 0; tn < 4; ++tn)
#pragma unroll
                        for (int r = 0; r < 4; ++r) {
                            int row = mb * 128 + wave * 32 + tm * 16 + quad * 4 + r;
                            int col = nb * 64 + tn * 16 + l16;
                            C[row * 512 + col] = f2bf(acc[tm][tn][r]);
                        }
            } else {
                // --- bias_comb core: bc[j] = sum_k W[j,k]*bsh[k] (raw bias
                //     added later by bias_fix) ---
                if (job == 72 || job == 73) {
                    const unsigned short* w = (const unsigned short*)
                        (ws + ((job == 72) ? WS_WSA : WS_WRA));
                    float* o = (float*)(ws + ((job == 72) ? WS_BCSA : WS_BCRA));
                    for (int j = tid; j < 512; j += 256) {
                        float s = 0.f;
                        for (int k = 0; k < HH; ++k) s += bf2f(w[j * HH + k]) * bsh[k];
                        o[j] = s;
                    }
                } else {
                    const unsigned short* w = (const unsigned short*)(ws + WS_WHPAD);
                    float* o = (float*)(ws + WS_BCH);
                    if (tid < 64) {
                        float s = 0.f;
                        for (int k = 0; k < HH; ++k) s += bf2f(w[tid * HH + k]) * bsh[k];
                        o[tid] = s;
                    }
                }
            }
            __syncthreads();    // protect s_job / LDS reuse across jobs
        }
        // (unreachable)
    }

    // ================= WINNER PATH: R7-exact LSTM loop =====================
    const unsigned short* xp    = (const unsigned short*)(ws + WS_XP);
    const unsigned short* wcat  = (const unsigned short*)(ws + WS_WCAT);
    const float*          biasc = (const float*)(ws + WS_BIASC);
    const unsigned short* cinit = (const unsigned short*)(ws + WS_CP);
    const unsigned short* h0s   = (const unsigned short*)(ws + WS_H0);
    unsigned short*       hx    = (unsigned short*)(ws + WS_HX);
    u32*                  flags = (u32*)(ws + WS_FLAGS);
    const int fl = (int)*(const unsigned int*)(ws + WS_FLAG);

    const int tid  = threadIdx.x;
    const int wave = tid >> 6, lane = tid & 63;
    const int quad = lane >> 4, l16 = lane & 15;
    const int mh = wave & 1, nh = wave >> 1;
    const int m = mh * 16 + l16;   // batch row for A frags

    // resident weight fragments: 2 n-tiles x 18 k-steps
    bf16x8 bw[2][18];
#pragma unroll
    for (int tn = 0; tn < 2; ++tn) {
        int nl   = nh * 32 + tn * 16 + l16;                 // local col [0,64)
        int gcol = (nl >> 4) * HH + g * 16 + (nl & 15);     // global gate col
        const unsigned short* wp = wcat + gcol * KK + quad * 8;
#pragma unroll
        for (int ks = 0; ks < 18; ++ks) bw[tn][ks] = ldb8(wp + ks * 32);
    }

    // epilogue: thread -> batch b, cell pair (cc, cc+1)
    const int b  = tid >> 3, pr = tid & 7, cc = pr * 2;
    const int n  = g * 16 + cc;                 // even global cell index
    const float bi0 = biasc[n],          bi1 = biasc[n + 1];
    const float bff0 = biasc[HH + n],    bff1 = biasc[HH + n + 1];
    const float bg0 = biasc[2*HH + n],   bg1 = biasc[2*HH + n + 1];
    const float bo0 = biasc[3*HH + n],   bo1 = biasc[3*HH + n + 1];
    float cst0 = bf2f(cinit[b * HH + n]);
    float cst1 = bf2f(cinit[b * HH + n + 1]);

    const unsigned short* xbase = xp + m * (TT * II) + quad * 8;
    bf16x8 ax0 = ldb8(xbase), ax1 = ldb8(xbase + 32);

    u32* myflag = flags + g * 32;               // own 128-B flag line
    u32* pollp  = flags + (lane & 31) * 32;     // lane j -> block j's line

    for (int t = 0; t < TT; ++t) {
        // x prefetch for t+1 issued first
        int tn1 = (t + 1 < TT) ? t + 1 : t;
        bf16x8 axn0 = ldb8(xbase + tn1 * II);
        bf16x8 axn1 = ldb8(xbase + tn1 * II + 32);

        // ---- A-frags for h(t-1): plain loads (fresh addresses -> L1 miss
        //      -> probe of the XCD's shared L2 which holds the stores) ----
        const unsigned short* hrow =
            (t == 0 ? h0s : hx + (t - 1) * (BB * HH)) + m * HH + quad * 8;
        bf16x8 a[16];
#pragma unroll
        for (int i = 0; i < 16; ++i) a[i] = ldb8(hrow + i * 32);

        // 4 independent 9-deep MFMA chains; x-terms first so they issue
        // while the h-loads are still in flight.
        f32x4 acc0  = {0.f, 0.f, 0.f, 0.f}, acc1  = {0.f, 0.f, 0.f, 0.f};
        f32x4 acc0b = {0.f, 0.f, 0.f, 0.f}, acc1b = {0.f, 0.f, 0.f, 0.f};
        __builtin_amdgcn_s_setprio(1);
        acc0  = __builtin_amdgcn_mfma_f32_16x16x32_bf16(ax0, bw[0][16], acc0,  0, 0, 0);
        acc1  = __builtin_amdgcn_mfma_f32_16x16x32_bf16(ax0, bw[1][16], acc1,  0, 0, 0);
        acc0b = __builtin_amdgcn_mfma_f32_16x16x32_bf16(ax1, bw[0][17], acc0b, 0, 0, 0);
        acc1b = __builtin_amdgcn_mfma_f32_16x16x32_bf16(ax1, bw[1][17], acc1b, 0, 0, 0);
#pragma unroll
        for (int i = 0; i < 8; ++i) {
            acc0  = __builtin_amdgcn_mfma_f32_16x16x32_bf16(a[i],     bw[0][i],     acc0,  0, 0, 0);
            acc1  = __builtin_amdgcn_mfma_f32_16x16x32_bf16(a[i],     bw[1][i],     acc1,  0, 0, 0);
            acc0b = __builtin_amdgcn_mfma_f32_16x16x32_bf16(a[i + 8], bw[0][i + 8], acc0b, 0, 0, 0);
            acc1b = __builtin_amdgcn_mfma_f32_16x16x32_bf16(a[i + 8], bw[1][i + 8], acc1b, 0, 0, 0);
        }
        __builtin_amdgcn_s_setprio(0);
        acc0 = acc0 + acc0b;
        acc1 = acc1 + acc1b;

        // ---- C-frag -> LDS (row = batch, col = quad*16 + local cell) ----
        {
            int row = mh * 16 + quad * 4;
#pragma unroll
            for (int r = 0; r < 4; ++r) gbuf[row + r][nh * 32 + l16]      = acc0[r];
#pragma unroll
            for (int r = 0; r < 4; ++r) gbuf[row + r][nh * 32 + 16 + l16] = acc1[r];
        }
        __syncthreads();    // sync A: gbuf ready

        // ---- epilogue: 2 adjacent cells per thread, one u32 h-store ----
        {
            float2 giv = *(const float2*)&gbuf[b][cc];
            float2 gfv = *(const float2*)&gbuf[b][16 + cc];
            float2 ggv = *(const float2*)&gbuf[b][32 + cc];
            float2 gov = *(const float2*)&gbuf[b][48 + cc];
            cst0 = sigf(gfv.x + bff0) * cst0 + sigf(giv.x + bi0) * tanhfast(ggv.x + bg0);
            cst1 = sigf(gfv.y + bff1) * cst1 + sigf(giv.y + bi1) * tanhfast(ggv.y + bg1);
            float h0v = sigf(gov.x + bo0) * tanhfast(cst0);
            float h1v = sigf(gov.y + bo1) * tanhfast(cst1);
            u32 hp = (u32)f2bf(h0v) | ((u32)f2bf(h1v) << 16);
            *(u32*)&hx[t * (BB * HH) + b * HH + n] = hp;   // h(t) -> slab t
            if (t == TT - 1) {
                if (fl) {
                    ((float*)dout)[HT_OFF + b * HH + n]     = h0v;
                    ((float*)dout)[HT_OFF + b * HH + n + 1] = h1v;
                    ((float*)dout)[CT_OFF + b * HH + n]     = cst0;
                    ((float*)dout)[CT_OFF + b * HH + n + 1] = cst1;
                } else {
                    ((u32*)dout)[(HT_OFF + b * HH + n) >> 1] = hp;
                    ((u32*)dout)[(CT_OFF + b * HH + n) >> 1] =
                        (u32)f2bf(cst0) | ((u32)f2bf(cst1) << 16);
                }
            }
        }
        __syncthreads();    // sync B: drains (vmcnt 0) all waves' h stores;
                            // also separates gbuf reads from next-step writes

        // ---- post flag: real RMW (+1), executes in the shared L2 ----
        if (tid == 0)
            (void)__hip_atomic_fetch_add(myflag, 1u, __ATOMIC_RELAXED,
                                         __HIP_MEMORY_SCOPE_WORKGROUP);

        // ---- wave 0 polls all 32 flags via sc1 loads (L1-bypass); then
        //      releases siblings through LDS s_go (no barrier).  Values:
        //      t+1 = go, TT+2 = poison (watchdog tripped somewhere). ----
        u32 die = 0u;
        if (wave == 0) {
            const u32 tgt = (u32)(t + 1);
            int it = 0;
            for (;;) {
                u32 v = (lane < 32)
                    ? __hip_atomic_load(pollp, __ATOMIC_RELAXED, __HIP_MEMORY_SCOPE_AGENT)
                    : tgt;
                if (__all((int)(v >= tgt))) break;
                if (++it > (1 << 17)) { die = 1u; break; }   // watchdog
            }
            if (lane == 0) {
                if (die)
                    __hip_atomic_store(myflag, (u32)(TT + 2), __ATOMIC_RELAXED,
                                       __HIP_MEMORY_SCOPE_AGENT);   // free peers
                __hip_atomic_store(&s_go, die ? (u32)(TT + 2) : (u32)(t + 1),
                                   __ATOMIC_RELAXED, __HIP_MEMORY_SCOPE_WORKGROUP);
            }
        } else {
            const u32 tgt = (u32)(t + 1);
            int it = 0; u32 v;
            for (;;) {
                v = __hip_atomic_load(&s_go, __ATOMIC_RELAXED,
                                      __HIP_MEMORY_SCOPE_WORKGROUP);
                if (v >= tgt) break;
                if (++it > (1 << 21)) { v = (u32)(TT + 2); break; }  // bounded
            }
            if (v >= (u32)(TT + 1)) die = 1u;   // poison (normal max is TT)
        }
        if (die) break;     // wave-uniform; fail fast, never hang
        asm volatile("" ::: "memory");
        ax0 = axn0; ax1 = axn1;                 // rotate x prefetch
    }
}

// ---------------------------------------------------------------------------
// raw-bias add fixup for the combined biases computed inside lstm_k's loser
// path (they hold only W@b_sh; add b_sa/b_ra/b_st/b_rw here, dtype-aware).
// ---------------------------------------------------------------------------
__global__ void bias_fix(const void* b_sa, const void* b_ra,
                         const void* b_st, const void* b_rw, char* ws) {
    const int fl = (int)*(const unsigned int*)(ws + WS_FLAG);
    int j = threadIdx.x;                 // 512 threads
    if (blockIdx.x == 0)      ((float*)(ws + WS_BCSA))[j] += loadf(b_sa, j, fl);
    else if (blockIdx.x == 1) ((float*)(ws + WS_BCRA))[j] += loadf(b_ra, j, fl);
    else if (j < 64)
        ((float*)(ws + WS_BCH))[j] += (j < FF) ? loadf(b_st, j, fl) : loadf(b_rw, 0, fl);
}

// ---------------------------------------------------------------------------
// Fused tail GEMM over A = routs [MM x 512] (t-major hx ring).
// R9: A-REUSE PAIRING.  grid (9, 256): blockIdx.x = j (FASTEST), blockIdx.y
// = mb.  j 0..7: ONE block computes BOTH the wcsa tile (rows j*64, ->es)
// and the wcra tile (rows (j+8)*64, ->er) — the A-tile is loaded ONCE for
// both, halving A traffic (544 -> 288 MB).  j == 8: proj head (whc, bf16).
// ---------------------------------------------------------------------------
__global__ __launch_bounds__(256)
void gemm_tail(const unsigned short* __restrict__ A,
               const unsigned short* __restrict__ Wes,   // wcsa|wcra stacked, 1024 rows
               const float* __restrict__ bes,            // bcsa|bcra f32[1024]
               const unsigned short* __restrict__ vvs,   // vs|vr bf16[1024]
               float* __restrict__ eout,                 // es|er f32[2*MM]
               const unsigned short* __restrict__ Wpj,   // whc
               const float* __restrict__ bpj,            // bch f32[64]
               unsigned short* __restrict__ proj) {
    __shared__ unsigned short As[128][72];
    __shared__ unsigned short Bs[2][64][72];
    const int tid = threadIdx.x;
    const int wave = tid >> 6, lane = tid & 63, quad = lane >> 4, l16 = lane & 15;
    const int j = blockIdx.x, mb = blockIdx.y;

    if (j == 8) {
        // ---------------- proj path (whc, rows 0..63) ----------------
        f32x4 acc[2][4];
#pragma unroll
        for (int tm = 0; tm < 2; ++tm)
#pragma unroll
            for (int tn = 0; tn < 4; ++tn) acc[tm][tn] = (f32x4){0.f, 0.f, 0.f, 0.f};
        for (int k0 = 0; k0 < 512; k0 += 64) {
#pragma unroll
            for (int i = 0; i < 4; ++i) {
                int v = tid + i * 256;
                int rowa = v >> 3, kc = (v & 7) * 8;
                *(uint4a*)&As[rowa][kc] = *(const uint4a*)(A + (mb * 128 + rowa) * 512 + k0 + kc);
            }
#pragma unroll
            for (int i = 0; i < 2; ++i) {
                int v = tid + i * 256;
                int rowb = v >> 3, kc = (v & 7) * 8;
                *(uint4a*)&Bs[0][rowb][kc] = *(const uint4a*)(Wpj + rowb * 512 + k0 + kc);
            }
            __syncthreads();
#pragma unroll
            for (int ks = 0; ks < 2; ++ks) {
                bf16x8 a0 = ldb8(&As[wave * 32 + l16][ks * 32 + quad * 8]);
                bf16x8 a1 = ldb8(&As[wave * 32 + 16 + l16][ks * 32 + quad * 8]);
#pragma unroll
                for (int tn = 0; tn < 4; ++tn) {
                    bf16x8 bb = ldb8(&Bs[0][tn * 16 + l16][ks * 32 + quad * 8]);
                    acc[0][tn] = __builtin_amdgcn_mfma_f32_16x16x32_bf16(a0, bb, acc[0][tn], 0, 0, 0);
                    acc[1][tn] = __builtin_amdgcn_mfma_f32_16x16x32_bf16(a1, bb, acc[1][tn], 0, 0, 0);
                }
            }
            __syncthreads();
        }
#pragma unroll
        for (int tm = 0; tm < 2; ++tm)
#pragma unroll
            for (int tn = 0; tn < 4; ++tn)
#pragma unroll
                for (int r = 0; r < 4; ++r) {
                    int row = mb * 128 + wave * 32 + tm * 16 + quad * 4 + r;
                    int col = tn * 16 + l16;
                    proj[row * 64 + col] = f2bf(acc[tm][tn][r] + bpj[col]);
                }
        return;
    }

    // ---------------- paired es/er path (A loaded once) ----------------
    f32x4 acc[2][2][4];    // [h][tm][tn], h=0 -> es (rows j*64), h=1 -> er
#pragma unroll
    for (int h = 0; h < 2; ++h)
#pragma unroll
        for (int tm = 0; tm < 2; ++tm)
#pragma unroll
            for (int tn = 0; tn < 4; ++tn) acc[h][tm][tn] = (f32x4){0.f, 0.f, 0.f, 0.f};

    for (int k0 = 0; k0 < 512; k0 += 64) {
#pragma unroll
        for (int i = 0; i < 4; ++i) {
            int v = tid + i * 256;
            int rowa = v >> 3, kc = (v & 7) * 8;
            *(uint4a*)&As[rowa][kc] = *(const uint4a*)(A + (mb * 128 + rowa) * 512 + k0 + kc);
        }
#pragma unroll
        for (int h = 0; h < 2; ++h)
#pragma unroll
            for (int i = 0; i < 2; ++i) {
                int v = tid + i * 256;
                int rowb = v >> 3, kc = (v & 7) * 8;
                *(uint4a*)&Bs[h][rowb][kc] =
                    *(const uint4a*)(Wes + ((j + 8 * h) * 64 + rowb) * 512 + k0 + kc);
            }
        __syncthreads();
#pragma unroll
        for (int ks = 0; ks < 2; ++ks) {
            bf16x8 a0 = ldb8(&As[wave * 32 + l16][ks * 32 + quad * 8]);
            bf16x8 a1 = ldb8(&As[wave * 32 + 16 + l16][ks * 32 + quad * 8]);
#pragma unroll
            for (int h = 0; h < 2; ++h)
#pragma unroll
                for (int tn = 0; tn < 4; ++tn) {
                    bf16x8 bb = ldb8(&Bs[h][tn * 16 + l16][ks * 32 + quad * 8]);
                    acc[h][0][tn] = __builtin_amdgcn_mfma_f32_16x16x32_bf16(a0, bb, acc[h][0][tn], 0, 0, 0);
                    acc[h][1][tn] = __builtin_amdgcn_mfma_f32_16x16x32_bf16(a1, bb, acc[h][1][tn], 0, 0, 0);
                }
        }
        __syncthreads();
    }
#pragma unroll
    for (int h = 0; h < 2; ++h) {
        const int eoff = h ? MM : 0;            // es | er (contiguous)
        float vcol[4], bcol[4];
#pragma unroll
        for (int tn = 0; tn < 4; ++tn) {
            int col = (j + 8 * h) * 64 + tn * 16 + l16;
            vcol[tn] = bf2f(vvs[col]); bcol[tn] = bes[col];
        }
#pragma unroll
        for (int tm = 0; tm < 2; ++tm)
#pragma unroll
            for (int r = 0; r < 4; ++r) {
                float s = 0.f;
#pragma unroll
                for (int tn = 0; tn < 4; ++tn)
                    s += vcol[tn] * tanhfast(acc[h][tm][tn][r] + bcol[tn]);
                s += __shfl_xor(s, 1); s += __shfl_xor(s, 2);
                s += __shfl_xor(s, 4); s += __shfl_xor(s, 8);
                if (l16 == 0) {
                    int row = mb * 128 + wave * 32 + tm * 16 + quad * 4 + r;
                    atomicAdd(&eout[eoff + row], s);
                }
            }
    }
}

// ---------------------------------------------------------------------------
// Online-softmax cumulative scan, software-pipelined.
// Reads row index t*32+b (t-major); writes original (b,t) layout.
// bv_sa / bv_ra are folded in HERE (es/er are zero-initialized + atomics).
// ---------------------------------------------------------------------------
__global__ __launch_bounds__(64)
void cumsum_k(char* __restrict__ ws, void* __restrict__ dout) {
    const unsigned short* proj = (const unsigned short*)(ws + WS_PROJ);
    const float* es = (const float*)(ws + WS_ES);
    const float* er = (const float*)(ws + WS_ER);
    const float* scal = (const float*)(ws + WS_SCAL);
    const int fl = (int)*(const unsigned int*)(ws + WS_FLAG);
    const int b = blockIdx.x, lane = threadIdx.x;
    const bool isr = (lane == 63);
    const float bv = isr ? scal[1] : scal[0];
    float m_ = -3e38f, d_ = 0.f, n_ = 0.f;
    float pj = bf2f(proj[b * 64 + lane]);       // row t=0 -> index b
    float e  = (isr ? er[b] : es[b]) + bv;
    for (int t = 0; t < TT; ++t) {
        float pjn = 0.f, en = 0.f;
        if (t + 1 < TT) {                       // prefetch next row (t+1)*32+b
            int rn = (t + 1) * BB + b;
            pjn = bf2f(proj[rn * 64 + lane]);
            en  = (isr ? er[rn] : es[rn]) + bv;
        }
        float mn = fmaxf(m_, e);
        float al = __expf(m_ - mn);
        float p  = __expf(e - mn);
        d_ = d_ * al + p;
        n_ = n_ * al + p * pj;
        m_ = mn;
        float o = n_ / d_;
        int rout = b * TT + t;
        int addr = isr ? (RW_OFF + rout) : (rout * FF + lane);
        if (fl) ((float*)dout)[addr] = o;
        else    ((unsigned short*)dout)[addr] = f2bf(o);
        pj = pjn; e = en;
    }
}

// ---------------------------------------------------------------------------
extern "C" void kernel_launch(void* const* d_in, const int* in_sizes, int n_in,
                              void* d_out, int out_size, void* d_ws, size_t ws_size,
                              hipStream_t stream) {
    const void* x    = d_in[0];
    const void* h0   = d_in[2];
    const void* c0   = d_in[3];
    const void* w_ih = d_in[4];
    const void* w_hh = d_in[5];
    const void* b_ih = d_in[6];
    const void* b_hh = d_in[7];
    const void* w_sh = d_in[8];
    const void* b_sh = d_in[9];
    const void* w_sa = d_in[10];
    const void* b_sa = d_in[11];
    const void* v_sa = d_in[12];
    const void* bv_sa= d_in[13];
    const void* w_ra = d_in[14];
    const void* b_ra = d_in[15];
    const void* v_ra = d_in[16];
    const void* bv_ra= d_in[17];
    const void* w_st = d_in[18];
    const void* b_st = d_in[19];
    const void* w_rw = d_in[20];
    const void* b_rw = d_in[21];

    char* ws = (char*)d_ws;
    unsigned short* wcsa  = (unsigned short*)(ws + WS_WCSA);
    unsigned short* whc   = (unsigned short*)(ws + WS_WHC);
    unsigned short* routs = (unsigned short*)(ws + WS_HX);   // t-major h ring
    unsigned short* proj  = (unsigned short*)(ws + WS_PROJ);
    unsigned short* vs    = (unsigned short*)(ws + WS_VS);
    float* bcsa = (float*)(ws + WS_BCSA);
    float* bch  = (float*)(ws + WS_BCH);
    float* es   = (float*)(ws + WS_ES);

    (void)hipMemsetAsync(d_ws, 0, 8448, stream);             // flags + dtype + tick/chosen + tick2
    (void)hipMemsetAsync(ws + WS_ES, 0, 2 * MM * 4, stream); // es|er accumulators
    sniff_k<<<1, 64, 0, stream>>>((const unsigned short*)x, (unsigned int*)(ws + WS_FLAG));
    prep_all<<<1024, 256, 0, stream>>>(x, h0, c0, w_sh, w_sa, w_ra, w_st, w_rw,
                                       v_sa, v_ra, b_sh, bv_sa, bv_ra, ws);
    prep_w<<<G4H, 256, 0, stream>>>(w_hh, w_ih, b_ih, b_hh, ws);

    // sequential LSTM: 32 winner blocks on one XCD; 224 losers absorb the
    // weight-combine GEMMs + bias combines in parallel on the idle XCDs.
    lstm_k<<<256, 256, 0, stream>>>(ws, d_out);

    // add raw biases to the loser-computed combined biases (cheap fixup)
    bias_fix<<<3, 512, 0, stream>>>(b_sa, b_ra, b_st, b_rw, ws);

    // fused tail: e_s, e_r AND proj in one pass over A (j fastest; es/er
    // tiles paired per block so A is loaded once for both)
    gemm_tail<<<dim3(9, 256), 256, 0, stream>>>(routs, wcsa, bcsa, vs, es,
                                                whc, bch, proj);
    // online-softmax causal scan -> state_outs + reward_outs
    cumsum_k<<<BB, 64, 0, stream>>>(ws, d_out);
}